// Round 8
// baseline (11285.446 us; speedup 1.0000x reference)
//
#include <hip/hip_runtime.h>
#include <hip/hip_bf16.h>

#define Bsz 256
#define Tlen 512
#define Dd 512
#define Hh 1024
#define G4 4096
#define NOUT 8
#define BT (Bsz * Tlen)

typedef short s16x8 __attribute__((ext_vector_type(8)));
typedef unsigned short u16x8 __attribute__((ext_vector_type(8)));
typedef float f32x4 __attribute__((ext_vector_type(4)));
typedef uint u32x4 __attribute__((ext_vector_type(4)));

__device__ __forceinline__ ushort f2bf(float f) {
    union { float f; uint u; } v; v.f = f;
    uint u = v.u;
    uint r = u + 0x7FFFu + ((u >> 16) & 1u);   // round-to-nearest-even
    return (ushort)(r >> 16);
}
__device__ __forceinline__ float bf2f(ushort u) {
    union { uint u; float f; } v; v.u = ((uint)u) << 16; return v.f;
}
__device__ __forceinline__ float sigf(float x) { return 1.f / (1.f + __expf(-x)); }
__device__ __forceinline__ float tanhfast(float x) {
    float ax = fabsf(x);
    float e = __expf(-2.f * ax);
    float t = (1.f - e) / (1.f + e);
    return copysignf(t, x);
}
__device__ __forceinline__ void gload16(const void* g, void* l) {
    __builtin_amdgcn_global_load_lds(
        (const __attribute__((address_space(1))) uint*)g,
        (__attribute__((address_space(3))) uint*)l, 16, 0, 0);
}
// ---- device-coherent (L2-bypassing) ops for cross-XCD h handoff ----
__device__ __forceinline__ u32x4 scload16(const void* p) {
    u32x4 r;
    asm volatile("global_load_dwordx4 %0, %1, off sc0 sc1" : "=&v"(r) : "v"(p));
    return r;
}
__device__ __forceinline__ int scload_u32(const int* p) {
    int r;
    asm volatile("global_load_dword %0, %1, off sc0 sc1\n\ts_waitcnt vmcnt(0)"
                 : "=&v"(r) : "v"(p) : "memory");
    return r;
}
__device__ __forceinline__ void scstore_u32(uint* p, uint v) {
    asm volatile("global_store_dword %0, %1, off sc0 sc1" :: "v"(p), "v"(v) : "memory");
}
__device__ __forceinline__ u16x8 pack8(const float4& a, const float4& b) {
    u16x8 o;
    o[0]=f2bf(a.x); o[1]=f2bf(a.y); o[2]=f2bf(a.z); o[3]=f2bf(a.w);
    o[4]=f2bf(b.x); o[5]=f2bf(b.y); o[6]=f2bf(b.z); o[7]=f2bf(b.w);
    return o;
}

// ---------------- init: zero h slot0 (bf16) and c/flags MB ----------------
__global__ void init_kernel(uint4* __restrict__ h0, uint4* __restrict__ c) {
    int i = blockIdx.x * 256 + threadIdx.x;       // 65536 threads
    uint4 z = make_uint4(0u, 0u, 0u, 0u);
    c[i] = z;                                     // 1 MB (c for fallback / flags for main)
    if (i < 32768) h0[i] = z;                     // 512 KB
}

// ---------------- fp32 -> bf16 convert (layout-preserving) ----------------
__global__ void cvt_kernel(const float4* __restrict__ src, ushort4* __restrict__ dst, int n4) {
    int i = blockIdx.x * 256 + threadIdx.x;
    if (i >= n4) return;
    float4 v = src[i];
    ushort4 o;
    o.x = f2bf(v.x); o.y = f2bf(v.y); o.z = f2bf(v.z); o.w = f2bf(v.w);
    dst[i] = o;
}

// ---------------- chunk convert (fallback T2) ----------------
__global__ void cvt_xchunk(const float* __restrict__ x, ushort* __restrict__ dst, int t0) {
    int gid = blockIdx.x * 256 + threadIdx.x;
    int k8  = gid & 63;
    int tl  = (gid >> 6) & 7;
    int row = gid >> 9;
    const float* s = x + ((size_t)row * Tlen + t0 + tl) * Dd + k8 * 8;
    float4 v0 = *(const float4*)s;
    float4 v1 = *(const float4*)(s + 4);
    *(u16x8*)(dst + ((size_t)row * 8 + tl) * Dd + k8 * 8) = pack8(v0, v1);
}

// ================= PERSISTENT LSTM (no grid.sync, no cache-maintenance) =================
// 256 blocks x 512 thr (coop launch => co-resident, 1 block/CU). Block owns (bt,jt)
// for all 512 steps; inner loop = r4's 6-round dbuf structure. Weights stay L2-warm
// (normal loads, no kernel boundary, no acquire fences). h handoff via sc0sc1
// write-through stores + L2-bypassing loads (L3-coherent). Per-step sync: per-bt
// group of 64 blocks, flag[bid]=t after vmcnt(0)+barrier; 64-lane sc-poll.
__launch_bounds__(512, 1)
__global__ void lstm_persist(const float* __restrict__ x,      // [256][512][512] f32
                             const ushort* __restrict__ Wih,   // bf16 [4096][512]
                             const ushort* __restrict__ Whh,   // bf16 [4096][1024]
                             const float* __restrict__ b_ih,
                             const float* __restrict__ b_hh,
                             ushort* __restrict__ hbuf,        // 2 slots [256][1024] bf16
                             int* __restrict__ flags) {        // [256]
    __shared__ char smem[131072];
    __shared__ float c_lds[1024];
    __shared__ float bias_lds[64];

    const int tid  = threadIdx.x;
    const int lane = tid & 63;
    const int w    = tid >> 6;       // 0..7
    const int g    = w >> 1;         // K-group 0..3 (K-slice [384g, 384g+384))
    const int ab   = w & 1;          // 0: stage A / cols 0..31, 1: stage B / cols 32..63
    const int B    = blockIdx.x;
    const int xcd  = B & 7, slot = B >> 3;
    const int jt   = xcd * 8 + (slot >> 2);    // 0..63
    const int bt   = slot & 3;                 // 0..3
    const int b0   = bt * 64;
    // group member bids for bt (lane enumerates jt)
    const int bidl = (lane >> 3) + ((lane & 7) << 5) + (bt << 3);

    for (int i = tid; i < 1024; i += 512) c_lds[i] = 0.f;
    if (tid < 64) {
        int gcol = (tid >> 4) * 1024 + jt * 16 + (tid & 15);
        bias_lds[tid] = b_ih[gcol] + b_hh[gcol];
    }
    __syncthreads();

    char* Abase0 = smem + g * 32768;
    float4 xv[16];
    u32x4  hv[8];

    #pragma unroll 1
    for (int t = 1; t <= Tlen; ++t) {
        const ushort* hrd = hbuf + (size_t)((t - 1) & 1) * (Bsz * Hh);
        ushort*       hwr = hbuf + (size_t)(t & 1) * (Bsz * Hh);

        f32x4 acc[4][2] = {};

        // issue chunk it's loads (A-wave -> regs, B-wave -> gload_lds into buf it&1)
        auto ISSUE = [&](int it) {
            const int k0 = g * 384 + it * 64;
            if (ab == 0) {
                if (k0 < Dd) {
                    #pragma unroll
                    for (int q = 0; q < 8; ++q) {
                        int row = q * 8 + (lane >> 3);
                        int cs  = (lane & 7) ^ (row & 7);
                        const float* p = x + ((size_t)(b0 + row) * Tlen + (t - 1)) * Dd + k0 + cs * 8;
                        xv[2*q]   = *(const float4*)p;
                        xv[2*q+1] = *(const float4*)(p + 4);
                    }
                } else {
                    #pragma unroll
                    for (int q = 0; q < 8; ++q) {
                        int row = q * 8 + (lane >> 3);
                        int cs  = (lane & 7) ^ (row & 7);
                        const ushort* p = hrd + (size_t)(b0 + row) * Hh + (k0 - Dd) + cs * 8;
                        hv[q] = scload16(p);
                    }
                }
            } else {
                char* Bb = Abase0 + (it & 1) * 16384 + 8192;
                #pragma unroll
                for (int q = 0; q < 8; ++q) {
                    int col = q * 8 + (lane >> 3);
                    int cs  = (lane & 7) ^ (col & 7);
                    int grow = ((col >> 4) << 10) + (jt << 4) + (col & 15);
                    const ushort* p = (k0 < Dd)
                        ? Wih + (size_t)grow * Dd + k0 + cs * 8
                        : Whh + (size_t)grow * Hh + (k0 - Dd) + cs * 8;
                    gload16(p, Bb + q * 1024);
                }
            }
        };
        // A-wave: complete chunk it into LDS buf it&1
        auto WRITE = [&](int it) {
            if (ab != 0) return;
            const int k0 = g * 384 + it * 64;
            char* Ab = Abase0 + (it & 1) * 16384;
            if (k0 < Dd) {
                #pragma unroll
                for (int q = 0; q < 8; ++q)
                    *(u16x8*)(Ab + q * 1024 + lane * 16) = pack8(xv[2*q], xv[2*q+1]);
            } else {
                asm volatile("s_waitcnt vmcnt(0)" ::: "memory");
                __builtin_amdgcn_sched_barrier(0);
                #pragma unroll
                for (int q = 0; q < 8; ++q)
                    *(u32x4*)(Ab + q * 1024 + lane * 16) = hv[q];
            }
        };
        auto COMPUTE = [&](int buf) {
            const char* Ab = Abase0 + buf * 16384;
            const char* Bb = Ab + 8192;
            #pragma unroll
            for (int ks = 0; ks < 2; ++ks) {
                const int kc = (ks << 2) + (lane >> 4);
                s16x8 a[4], bb2[2];
                #pragma unroll
                for (int m = 0; m < 4; ++m) {
                    int row = (m << 4) + (lane & 15);
                    a[m] = *(const s16x8*)(Ab + row * 128 + ((kc ^ (row & 7)) << 4));
                }
                #pragma unroll
                for (int n = 0; n < 2; ++n) {
                    int col = (ab << 5) + (n << 4) + (lane & 15);
                    bb2[n] = *(const s16x8*)(Bb + col * 128 + ((kc ^ (col & 7)) << 4));
                }
                #pragma unroll
                for (int m = 0; m < 4; ++m)
                    #pragma unroll
                    for (int n = 0; n < 2; ++n)
                        acc[m][n] = __builtin_amdgcn_mfma_f32_16x16x32_bf16(a[m], bb2[n], acc[m][n], 0, 0, 0);
            }
        };

        ISSUE(0);
        WRITE(0);
        __syncthreads();
        #pragma unroll
        for (int it = 0; it < 6; ++it) {
            if (it < 5) ISSUE(it + 1);     // loads in flight under compute (T14)
            COMPUTE(it & 1);
            if (it < 5) WRITE(it + 1);     // nxt buf: no reader until after barrier
            __syncthreads();
        }

        // ---- partials: group g -> LDS (reuse tile region) ----
        float* bw = (float*)smem + g * (64 * 68);
        #pragma unroll
        for (int m = 0; m < 4; ++m)
            #pragma unroll
            for (int n = 0; n < 2; ++n)
                #pragma unroll
                for (int j = 0; j < 4; ++j) {
                    int row = (m << 4) + ((lane >> 4) << 2) + j;
                    int col = (ab << 5) + (n << 4) + (lane & 15);
                    bw[row * 68 + col] = acc[m][n][j];
                }
        __syncthreads();

        // ---- reduce 4 partials + activations + cell update + sc h-store ----
        {
            const float* part = (const float*)smem;
            const int cell0 = tid * 2;
            const int row = cell0 >> 4;
            const int cv  = cell0 & 15;            // even
            float gv[2][4];
            #pragma unroll
            for (int u = 0; u < 2; ++u) {
                gv[u][0] = bias_lds[cv + u];
                gv[u][1] = bias_lds[16 + cv + u];
                gv[u][2] = bias_lds[32 + cv + u];
                gv[u][3] = bias_lds[48 + cv + u];
            }
            #pragma unroll
            for (int p = 0; p < 4; ++p) {
                const float* bb = part + p * (64 * 68) + row * 68;
                #pragma unroll
                for (int u = 0; u < 2; ++u) {
                    gv[u][0] += bb[cv + u];
                    gv[u][1] += bb[16 + cv + u];
                    gv[u][2] += bb[32 + cv + u];
                    gv[u][3] += bb[48 + cv + u];
                }
            }
            ushort hn[2];
            #pragma unroll
            for (int u = 0; u < 2; ++u) {
                float i_ = sigf(gv[u][0]), f_ = sigf(gv[u][1]);
                float g_ = tanhfast(gv[u][2]), o_ = sigf(gv[u][3]);
                float cn = f_ * c_lds[row * 16 + cv + u] + i_ * g_;
                c_lds[row * 16 + cv + u] = cn;
                hn[u] = f2bf(o_ * tanhfast(cn));
            }
            uint pack = (uint)hn[0] | ((uint)hn[1] << 16);
            scstore_u32((uint*)(hwr + (size_t)(b0 + row) * Hh + (jt << 4) + cv), pack);
        }

        asm volatile("s_waitcnt vmcnt(0)" ::: "memory");   // h at L3
        __syncthreads();                                   // all waves' stores done
        if (tid == 0) scstore_u32((uint*)&flags[B], (uint)t);
        // poll group flags (all 64 jt blocks of this bt)
        for (;;) {
            int v = scload_u32(&flags[bidl]);
            if (__all(v >= t)) break;
            __builtin_amdgcn_s_sleep(4);
        }
    }
}

// ---------------- r4 step kernel (fallback main path) ----------------
__launch_bounds__(512, 2)
__global__ void lstm_step3(const ushort* __restrict__ xsrc, int tstride, int tloc,
                           const ushort* __restrict__ Wih,
                           const ushort* __restrict__ Whh,
                           const ushort* __restrict__ h_prev,
                           ushort* __restrict__ h_next,
                           float* __restrict__ c,
                           const float* __restrict__ b_ih,
                           const float* __restrict__ b_hh) {
    __shared__ char smem[131072];
    __shared__ float bias_lds[64];

    const int tid  = threadIdx.x;
    const int lane = tid & 63;
    const int w    = tid >> 6;
    const int g    = w >> 1;
    const int ab   = w & 1;

    const int B   = blockIdx.x;
    const int xcd  = B & 7, slot = B >> 3;
    const int jt   = xcd * 8 + (slot >> 2);
    const int bt   = slot & 3;
    const int b0   = bt * 64;

    if (tid < 64) {
        int gcol = (tid >> 4) * 1024 + jt * 16 + (tid & 15);
        bias_lds[tid] = b_ih[gcol] + b_hh[gcol];
    }

    f32x4 acc[4][2] = {};

    auto STAGE = [&](int buf, int it) {
        const int k0 = (g * 6 + it) << 6;
        char* base = smem + g * 32768 + buf * 16384 + ab * 8192;
        if (ab == 0) {
            if (k0 < Dd) {
                #pragma unroll
                for (int q = 0; q < 8; ++q) {
                    int r  = q * 8 + (lane >> 3);
                    int cs = (lane & 7) ^ (r & 7);
                    const ushort* gp = xsrc + ((size_t)(b0 + r) * tstride + tloc) * Dd + k0 + cs * 8;
                    gload16(gp, base + q * 1024);
                }
            } else {
                #pragma unroll
                for (int q = 0; q < 8; ++q) {
                    int r  = q * 8 + (lane >> 3);
                    int cs = (lane & 7) ^ (r & 7);
                    const ushort* gp = h_prev + (size_t)(b0 + r) * Hh + (k0 - Dd) + cs * 8;
                    gload16(gp, base + q * 1024);
                }
            }
        } else {
            #pragma unroll
            for (int q = 0; q < 8; ++q) {
                int col = q * 8 + (lane >> 3);
                int cs  = (lane & 7) ^ (col & 7);
                int grow = (col >> 4) * 1024 + jt * 16 + (col & 15);
                const ushort* gp = (k0 < Dd)
                    ? (Wih + (size_t)grow * Dd + k0 + cs * 8)
                    : (Whh + (size_t)grow * Hh + (k0 - Dd) + cs * 8);
                gload16(gp, base + q * 1024);
            }
        }
    };
    auto COMPUTE = [&](int buf) {
        const char* Ab = smem + g * 32768 + buf * 16384;
        const char* Bb = Ab + 8192;
        #pragma unroll
        for (int ks = 0; ks < 2; ++ks) {
            const int kc = (ks << 2) + (lane >> 4);
            s16x8 a[4], bb[2];
            #pragma unroll
            for (int m = 0; m < 4; ++m) {
                int row = (m << 4) + (lane & 15);
                a[m] = *(const s16x8*)(Ab + row * 128 + ((kc ^ (row & 7)) << 4));
            }
            #pragma unroll
            for (int n = 0; n < 2; ++n) {
                int col = (ab << 5) + (n << 4) + (lane & 15);
                bb[n] = *(const s16x8*)(Bb + col * 128 + ((kc ^ (col & 7)) << 4));
            }
            #pragma unroll
            for (int m = 0; m < 4; ++m)
                #pragma unroll
                for (int n = 0; n < 2; ++n)
                    acc[m][n] = __builtin_amdgcn_mfma_f32_16x16x32_bf16(a[m], bb[n], acc[m][n], 0, 0, 0);
        }
    };

    STAGE(0, 0);
    __syncthreads();
    #pragma unroll
    for (int it = 0; it < 6; ++it) {
        if (it < 5) STAGE((it + 1) & 1, it + 1);
        COMPUTE(it & 1);
        __syncthreads();
    }

    float* bw = (float*)smem + g * (64 * 68);
    #pragma unroll
    for (int m = 0; m < 4; ++m)
        #pragma unroll
        for (int n = 0; n < 2; ++n)
            #pragma unroll
            for (int j = 0; j < 4; ++j) {
                int row = (m << 4) + ((lane >> 4) << 2) + j;
                int col = (ab << 5) + (n << 4) + (lane & 15);
                bw[row * 68 + col] = acc[m][n][j];
            }
    __syncthreads();

    const float* bufs = (const float*)smem;
    #pragma unroll
    for (int u = 0; u < 2; ++u) {
        int cell = tid * 2 + u;
        int row  = cell >> 4;
        int cv   = cell & 15;
        float gi = 0.f, gf = 0.f, gg = 0.f, go = 0.f;
        #pragma unroll
        for (int p = 0; p < 4; ++p) {
            const float* bb = bufs + p * (64 * 68) + row * 68;
            gi += bb[cv]; gf += bb[16 + cv]; gg += bb[32 + cv]; go += bb[48 + cv];
        }
        gi += bias_lds[cv];      gf += bias_lds[16 + cv];
        gg += bias_lds[32 + cv]; go += bias_lds[48 + cv];
        float i_ = sigf(gi), f_ = sigf(gf), g_ = tanhfast(gg), o_ = sigf(go);
        int gcol = jt * 16 + cv;
        size_t cidx = (size_t)(b0 + row) * Hh + gcol;
        float cn = f_ * c[cidx] + i_ * g_;
        c[cidx] = cn;
        h_next[cidx] = f2bf(o_ * tanhfast(cn));
    }
}

// ---------------- T3 fallback (proven round-0) ----------------
__launch_bounds__(256)
__global__ void lstm_step_fused(const float* __restrict__ x,
                          const ushort* __restrict__ Wih,
                          const ushort* __restrict__ Whh,
                          const float* __restrict__ b_ih,
                          const float* __restrict__ b_hh,
                          const ushort* __restrict__ h_prev,
                          ushort* __restrict__ h_next,
                          float* __restrict__ c,
                          int t) {
    __shared__ ushort At[64 * 64];
    __shared__ ushort Bt[64 * 64];
    __shared__ float gates[64 * 72];

    const int tid  = threadIdx.x;
    const int lane = tid & 63;
    const int wid  = tid >> 6;
    const int wr   = wid >> 1;
    const int wc   = wid & 1;
    const int bt   = blockIdx.x >> 6;
    const int jt   = blockIdx.x & 63;
    const int b0   = bt * 64;
    const int j0   = jt * 16;

    f32x4 acc[2][2] = {};

    auto mfma_tile = [&]() {
        #pragma unroll
        for (int ks = 0; ks < 2; ++ks) {
            const int kc = (ks << 2) + (lane >> 4);
            s16x8 a[2], bfr[2];
            #pragma unroll
            for (int m = 0; m < 2; ++m) {
                int row = wr * 32 + m * 16 + (lane & 15);
                a[m] = *(const s16x8*)&At[row * 64 + ((kc ^ (row & 7)) << 3)];
            }
            #pragma unroll
            for (int n = 0; n < 2; ++n) {
                int col = wc * 32 + n * 16 + (lane & 15);
                bfr[n] = *(const s16x8*)&Bt[col * 64 + ((kc ^ (col & 7)) << 3)];
            }
            #pragma unroll
            for (int m = 0; m < 2; ++m)
                #pragma unroll
                for (int n = 0; n < 2; ++n)
                    acc[m][n] = __builtin_amdgcn_mfma_f32_16x16x32_bf16(a[m], bfr[n], acc[m][n], 0, 0, 0);
        }
    };

    for (int kb = 0; kb < Dd; kb += 64) {
        __syncthreads();
        #pragma unroll
        for (int it = 0; it < 4; ++it) {
            int idx = tid + it * 256;
            int row = idx >> 4;
            int k   = (idx & 15) * 4;
            const float4 v = *(const float4*)&x[(size_t)(b0 + row) * (Tlen * Dd) + (size_t)t * Dd + kb + k];
            ushort4 o;
            o.x = f2bf(v.x); o.y = f2bf(v.y); o.z = f2bf(v.z); o.w = f2bf(v.w);
            int dst = row * 64 + (((k >> 3) ^ (row & 7)) << 3) + (k & 7);
            *(ushort4*)&At[dst] = o;
        }
        #pragma unroll
        for (int it = 0; it < 2; ++it) {
            int idx = tid + it * 256;
            int col = idx >> 3;
            int kc  = idx & 7;
            int grow = ((col >> 4) << 10) + j0 + (col & 15);
            uint4 v = *(const uint4*)&Wih[(size_t)grow * Dd + kb + kc * 8];
            *(uint4*)&Bt[col * 64 + ((kc ^ (col & 7)) << 3)] = v;
        }
        __syncthreads();
        mfma_tile();
    }
    for (int kb = 0; kb < Hh; kb += 64) {
        __syncthreads();
        #pragma unroll
        for (int it = 0; it < 2; ++it) {
            int idx = tid + it * 256;
            int row = idx >> 3;
            int kc  = idx & 7;
            uint4 v = *(const uint4*)&h_prev[(size_t)(b0 + row) * Hh + kb + kc * 8];
            *(uint4*)&At[row * 64 + ((kc ^ (row & 7)) << 3)] = v;
        }
        #pragma unroll
        for (int it = 0; it < 2; ++it) {
            int idx = tid + it * 256;
            int col = idx >> 3;
            int kc  = idx & 7;
            int grow = ((col >> 4) << 10) + j0 + (col & 15);
            uint4 v = *(const uint4*)&Whh[(size_t)grow * Hh + kb + kc * 8];
            *(uint4*)&Bt[col * 64 + ((kc ^ (col & 7)) << 3)] = v;
        }
        __syncthreads();
        mfma_tile();
    }

    #pragma unroll
    for (int m = 0; m < 2; ++m)
        #pragma unroll
        for (int n = 0; n < 2; ++n)
            #pragma unroll
            for (int j = 0; j < 4; ++j) {
                int row = wr * 32 + m * 16 + ((lane >> 4) << 2) + j;
                int col = wc * 32 + n * 16 + (lane & 15);
                gates[row * 72 + col] = acc[m][n][j];
            }
    __syncthreads();

    #pragma unroll
    for (int it = 0; it < 4; ++it) {
        int idx = tid + it * 256;
        int row = idx >> 4;
        int cc  = idx & 15;
        int gcol = j0 + cc;
        float gi = gates[row * 72 + cc]      + b_ih[gcol]          + b_hh[gcol];
        float gf = gates[row * 72 + 16 + cc] + b_ih[Hh + gcol]     + b_hh[Hh + gcol];
        float gg = gates[row * 72 + 32 + cc] + b_ih[2 * Hh + gcol] + b_hh[2 * Hh + gcol];
        float go = gates[row * 72 + 48 + cc] + b_ih[3 * Hh + gcol] + b_hh[3 * Hh + gcol];
        float i_ = sigf(gi);
        float f_ = sigf(gf);
        float g_ = tanhfast(gg);
        float o_ = sigf(go);
        size_t cidx = (size_t)(b0 + row) * Hh + gcol;
        float cn = f_ * c[cidx] + i_ * g_;
        c[cidx] = cn;
        float hn = o_ * tanhfast(cn);
        h_next[cidx] = f2bf(hn);
    }
}

// ---------------- FC head ----------------
__global__ void fc_kernel(const ushort* __restrict__ h,
                          const float* __restrict__ Wfc,
                          const float* __restrict__ bfc,
                          float* __restrict__ out) {
    int b = blockIdx.x;
    int w = threadIdx.x >> 6;
    int lane = threadIdx.x & 63;
    float s = 0.f;
    for (int k = lane; k < Hh; k += 64)
        s += bf2f(h[(size_t)b * Hh + k]) * Wfc[w * Hh + k];
    #pragma unroll
    for (int off = 32; off; off >>= 1) s += __shfl_down(s, off);
    if (lane == 0) out[b * NOUT + w] = sigf(s + bfc[w]);
}

// ================= LAUNCH =================

extern "C" void kernel_launch(void* const* d_in, const int* in_sizes, int n_in,
                              void* d_out, int out_size, void* d_ws, size_t ws_size,
                              hipStream_t stream) {
    const float* x    = (const float*)d_in[0];
    const float* W_ih = (const float*)d_in[1];
    const float* W_hh = (const float*)d_in[2];
    const float* b_ih = (const float*)d_in[3];
    const float* b_hh = (const float*)d_in[4];
    const float* W_fc = (const float*)d_in[5];
    const float* b_fc = (const float*)d_in[6];
    float* out = (float*)d_out;
    char* ws = (char*)d_ws;

    // ws layout:
    //   [0, 1 MB)    h ping-pong bf16 [2][256][1024]
    //   [1, 2 MB)    main: flags[256] ; fallback: c fp32
    //   [2, 6 MB)    W_ih bf16
    //   [6, 14 MB)   W_hh bf16
    //   [14 MB, ..)  fallback x bf16 (full 128 MB T1 / chunked 4 MB T2)
    ushort* h_buf  = (ushort*)ws;
    float*  c_ws   = (float*)(ws + (1ull << 20));
    int*    flags  = (int*)(ws + (1ull << 20));
    ushort* wih_bf = (ushort*)(ws + (2ull << 20));
    ushort* whh_bf = (ushort*)(ws + (6ull << 20));
    char*   x_ext  = ws + (14ull << 20);

    const size_t FIXED  = 14ull << 20;
    const size_t XFULL  = (size_t)Bsz * Tlen * Dd * 2;
    const size_t XCHUNK = (size_t)Bsz * 8 * Dd * 2;

    init_kernel<<<256, 256, 0, stream>>>((uint4*)h_buf, (uint4*)c_ws);
    cvt_kernel<<<(G4 * Dd / 4) / 256, 256, 0, stream>>>((const float4*)W_ih, (ushort4*)wih_bf, G4 * Dd / 4);
    cvt_kernel<<<(G4 * Hh / 4) / 256, 256, 0, stream>>>((const float4*)W_hh, (ushort4*)whh_bf, G4 * Hh / 4);

    // ---- main path: persistent cooperative kernel ----
    {
        void* args[] = { (void*)&x, (void*)&wih_bf, (void*)&whh_bf, (void*)&b_ih,
                         (void*)&b_hh, (void*)&h_buf, (void*)&flags };
        hipError_t err = hipLaunchCooperativeKernel((const void*)lstm_persist,
                                                    dim3(256), dim3(512), args, 0, stream);
        if (err == hipSuccess) {
            // t=512 wrote slot 0
            fc_kernel<<<256, 512, 0, stream>>>(h_buf, W_fc, b_fc, out);
            return;
        }
    }

    // ---- fallback: proven per-step path (r4) ----
    if (ws_size >= FIXED + XFULL) {
        ushort* x_bf = (ushort*)x_ext;
        const int n4 = BT * Dd / 4;
        cvt_kernel<<<n4 / 256, 256, 0, stream>>>((const float4*)x, (ushort4*)x_bf, n4);
        for (int t = 0; t < Tlen; ++t) {
            const ushort* hp = h_buf + (size_t)(t & 1) * Bsz * Hh;
            ushort*       hn = h_buf + (size_t)((t + 1) & 1) * Bsz * Hh;
            lstm_step3<<<256, 512, 0, stream>>>(x_bf, Tlen, t, wih_bf, whh_bf,
                                                hp, hn, c_ws, b_ih, b_hh);
        }
    } else if (ws_size >= FIXED + 2 * XCHUNK) {
        ushort* xchunk = (ushort*)x_ext;
        for (int t = 0; t < Tlen; ++t) {
            if ((t & 7) == 0) {
                ushort* dst = xchunk + (size_t)((t >> 3) & 1) * (Bsz * 8 * Dd);
                cvt_xchunk<<<512, 256, 0, stream>>>(x, dst, t);
            }
            const ushort* xb = xchunk + (size_t)((t >> 3) & 1) * (Bsz * 8 * Dd);
            const ushort* hp = h_buf + (size_t)(t & 1) * Bsz * Hh;
            ushort*       hn = h_buf + (size_t)((t + 1) & 1) * Bsz * Hh;
            lstm_step3<<<256, 512, 0, stream>>>(xb, 8, t & 7, wih_bf, whh_bf,
                                                hp, hn, c_ws, b_ih, b_hh);
        }
    } else {
        for (int t = 0; t < Tlen; ++t) {
            const ushort* hp = h_buf + (size_t)(t & 1) * Bsz * Hh;
            ushort*       hn = h_buf + (size_t)((t + 1) & 1) * Bsz * Hh;
            lstm_step_fused<<<256, 256, 0, stream>>>(x, wih_bf, whh_bf, b_ih, b_hh, hp, hn, c_ws, t);
        }
    }
    fc_kernel<<<256, 512, 0, stream>>>(h_buf, W_fc, b_fc, out);
}

// Round 9
// 6053.326 us; speedup vs baseline: 1.8643x; 1.8643x over previous
//
#include <hip/hip_runtime.h>
#include <hip/hip_bf16.h>

#define Bsz 256
#define Tlen 512
#define Dd 512
#define Hh 1024
#define G4 4096
#define NOUT 8
#define BT (Bsz * Tlen)

typedef short s16x8 __attribute__((ext_vector_type(8)));
typedef unsigned short u16x8 __attribute__((ext_vector_type(8)));
typedef float f32x4 __attribute__((ext_vector_type(4)));

__device__ __forceinline__ ushort f2bf(float f) {
    union { float f; uint u; } v; v.f = f;
    uint u = v.u;
    uint r = u + 0x7FFFu + ((u >> 16) & 1u);   // round-to-nearest-even
    return (ushort)(r >> 16);
}
__device__ __forceinline__ float bf2f(ushort u) {
    union { uint u; float f; } v; v.u = ((uint)u) << 16; return v.f;
}
__device__ __forceinline__ float sigf(float x) { return 1.f / (1.f + __expf(-x)); }
__device__ __forceinline__ float tanhfast(float x) {
    float ax = fabsf(x);
    float e = __expf(-2.f * ax);
    float t = (1.f - e) / (1.f + e);
    return copysignf(t, x);
}
__device__ __forceinline__ void gload16(const void* g, void* l) {
    __builtin_amdgcn_global_load_lds(
        (const __attribute__((address_space(1))) uint*)g,
        (__attribute__((address_space(3))) uint*)l, 16, 0, 0);
}

// ---------------- init: zero h0 (bf16, buffer 0) and c (fp32) ----------------
__global__ void init_kernel(uint4* __restrict__ h0, uint4* __restrict__ c) {
    int i = blockIdx.x * 256 + threadIdx.x;       // 65536 threads
    uint4 z = make_uint4(0u, 0u, 0u, 0u);
    c[i] = z;                                     // 1 MB
    if (i < 32768) h0[i] = z;                     // 512 KB
}

// ---------------- fp32 -> bf16 convert (layout-preserving) ----------------
__global__ void cvt_kernel(const float4* __restrict__ src, ushort4* __restrict__ dst, int n4) {
    int i = blockIdx.x * 256 + threadIdx.x;
    if (i >= n4) return;
    float4 v = src[i];
    ushort4 o;
    o.x = f2bf(v.x); o.y = f2bf(v.y); o.z = f2bf(v.z); o.w = f2bf(v.w);
    dst[i] = o;
}

// ---------------- chunk convert: x[:, t0..t0+7, :] fp32 -> [256][8][512] bf16 ----------------
__global__ void cvt_xchunk(const float* __restrict__ x, ushort* __restrict__ dst, int t0) {
    int gid = blockIdx.x * 256 + threadIdx.x;     // 131072 units of 8 elems
    int k8  = gid & 63;
    int tl  = (gid >> 6) & 7;
    int row = gid >> 9;                           // 0..255
    const float* s = x + ((size_t)row * Tlen + t0 + tl) * Dd + k8 * 8;
    float4 v0 = *(const float4*)s;
    float4 v1 = *(const float4*)(s + 4);
    u16x8 o;
    o[0]=f2bf(v0.x); o[1]=f2bf(v0.y); o[2]=f2bf(v0.z); o[3]=f2bf(v0.w);
    o[4]=f2bf(v1.x); o[5]=f2bf(v1.y); o[6]=f2bf(v1.z); o[7]=f2bf(v1.w);
    *(u16x8*)(dst + ((size_t)row * 8 + tl) * Dd + k8 * 8) = o;
}

// ---------------- one LSTM time step: 2 blocks/CU for cross-block overlap ----------------
// grid 512 = 8 bt x 64 jt (XCD remap), 256 threads (4 waves), tile 32x64.
// NO K-split: wave (wr,wc) owns its 16x32 output patch for the FULL K=1536 ->
// no partial reduction, acc = 2 x f32x4. K loop: 12 chunks of 128, LDS dbuf
// 2 x (A [32][128] 8KB + B [64][128] 16KB) = 48KB -> 2-3 blocks/CU. One block's
// barrier/staging stall hides under the other block's compute (m114 overlap).
__launch_bounds__(256, 2)
__global__ void lstm_step7(const ushort* __restrict__ xsrc, int tstride, int tloc,
                           const ushort* __restrict__ Wih,   // bf16 [4096][512]
                           const ushort* __restrict__ Whh,   // bf16 [4096][1024]
                           const ushort* __restrict__ h_prev,// bf16 [256][1024]
                           ushort* __restrict__ h_next,
                           float* __restrict__ c,            // fp32 [256][1024]
                           const float* __restrict__ b_ih,
                           const float* __restrict__ b_hh) {
    __shared__ char smem[49152];          // 2 bufs x (A 8KB + B 16KB); epilogue reuses
    __shared__ float bias_lds[64];

    const int tid  = threadIdx.x;
    const int lane = tid & 63;
    const int w    = tid >> 6;            // 0..3
    const int wr   = w >> 1;              // row half (16 rows)
    const int wc   = w & 1;               // col half (32 cols)
    const int B    = blockIdx.x;
    const int xcd  = B & 7, slot = B >> 3;       // XCD remap: 8 jts x 8 bts per XCD
    const int jt   = xcd * 8 + (slot >> 3);      // 0..63
    const int bt   = slot & 7;                   // 0..7
    const int b0   = bt * 32;

    if (tid < 64) {
        int gcol = (tid >> 4) * 1024 + jt * 16 + (tid & 15);
        bias_lds[tid] = b_ih[gcol] + b_hh[gcol];
    }

    const int rlo = lane & 15;

    // stage chunk it (k = it*128 .. +128) into buf: 6 gload16 per wave.
    // A: 8 instr-groups of 1KB (4 rows x 16 chunks); B: 16 instr-groups.
    auto STAGE = [&](int buf, int it) {
        const int k0 = it << 7;
        char* Abase = smem + buf * 24576;
        char* Bbase = Abase + 8192;
        #pragma unroll
        for (int i = 0; i < 2; ++i) {              // A: q = w*2+i in 0..7
            const int q   = (w << 1) + i;
            const int row = (q << 2) + (lane >> 4);
            const int cs  = rlo ^ (row & 7);
            const int k   = k0 + cs * 8;
            const ushort* p = (k0 < Dd)
                ? xsrc + ((size_t)(b0 + row) * tstride + tloc) * Dd + k
                : h_prev + (size_t)(b0 + row) * Hh + (k - Dd);
            gload16(p, Abase + (q << 10));
        }
        #pragma unroll
        for (int i = 0; i < 4; ++i) {              // B: q = w*4+i in 0..15
            const int q   = (w << 2) + i;
            const int col = (q << 2) + (lane >> 4);
            const int cs  = rlo ^ (col & 7);
            const int k   = k0 + cs * 8;
            const int grow = ((col >> 4) << 10) + (jt << 4) + (col & 15);
            const ushort* p = (k0 < Dd)
                ? Wih + (size_t)grow * Dd + k
                : Whh + (size_t)grow * Hh + (k - Dd);
            gload16(p, Bbase + (q << 10));
        }
    };

    f32x4 acc[2] = {};
    auto COMPUTE = [&](int buf) {
        const char* Ab = smem + buf * 24576;
        const char* Bb = Ab + 8192;
        const int arow  = (wr << 4) + rlo;         // 0..31
        const int bcol0 = (wc << 5) + rlo;         // base col for n=0
        #pragma unroll
        for (int ks = 0; ks < 4; ++ks) {
            const int kc = (ks << 2) + (lane >> 4);   // 0..15
            s16x8 a  = *(const s16x8*)(Ab + arow * 256 + ((kc ^ (arow & 7)) << 4));
            s16x8 b0v = *(const s16x8*)(Bb + bcol0 * 256 + ((kc ^ (bcol0 & 7)) << 4));
            s16x8 b1v = *(const s16x8*)(Bb + (bcol0 + 16) * 256 + ((kc ^ (bcol0 & 7)) << 4));
            acc[0] = __builtin_amdgcn_mfma_f32_16x16x32_bf16(a, b0v, acc[0], 0, 0, 0);
            acc[1] = __builtin_amdgcn_mfma_f32_16x16x32_bf16(a, b1v, acc[1], 0, 0, 0);
        }
    };

    STAGE(0, 0);
    __syncthreads();
    #pragma unroll
    for (int it = 0; it < 12; ++it) {
        if (it < 11) STAGE((it + 1) & 1, it + 1);  // issue next-chunk loads first
        COMPUTE(it & 1);
        __syncthreads();                            // next buf ready, cur reusable
    }

    // ---- epilogue: gates exchange (reuse LDS), activations, cell update ----
    float* gates = (float*)smem;                    // [32][68] f32 = 8.7 KB
    {
        const int q4 = (lane >> 4) << 2;
        #pragma unroll
        for (int n = 0; n < 2; ++n) {
            const int col = (wc << 5) + (n << 4) + rlo;
            #pragma unroll
            for (int j = 0; j < 4; ++j) {
                const int row = (wr << 4) + q4 + j;
                gates[row * 68 + col] = acc[n][j];
            }
        }
    }
    __syncthreads();

    const int cv = tid & 15;
    const int r0 = (tid >> 4) << 1;                 // 2 cells/thread: rows r0, r0+1
    #pragma unroll
    for (int u = 0; u < 2; ++u) {
        const int row = r0 + u;                     // 0..31
        const float* gr = gates + row * 68;
        float gi = gr[cv]      + bias_lds[cv];
        float gf = gr[16 + cv] + bias_lds[16 + cv];
        float gg = gr[32 + cv] + bias_lds[32 + cv];
        float go = gr[48 + cv] + bias_lds[48 + cv];
        float i_ = sigf(gi), f_ = sigf(gf), g_ = tanhfast(gg), o_ = sigf(go);
        const int gcol = (jt << 4) + cv;
        const size_t cidx = (size_t)(b0 + row) * Hh + gcol;
        float cn = f_ * c[cidx] + i_ * g_;
        c[cidx] = cn;
        h_next[cidx] = f2bf(o_ * tanhfast(cn));
    }
}

// ---------------- FALLBACK: proven round-0 fused step ----------------
__launch_bounds__(256)
__global__ void lstm_step_fused(const float* __restrict__ x,
                          const ushort* __restrict__ Wih,
                          const ushort* __restrict__ Whh,
                          const float* __restrict__ b_ih,
                          const float* __restrict__ b_hh,
                          const ushort* __restrict__ h_prev,
                          ushort* __restrict__ h_next,
                          float* __restrict__ c,
                          int t) {
    __shared__ ushort At[64 * 64];
    __shared__ ushort Bt[64 * 64];
    __shared__ float gates[64 * 72];

    const int tid  = threadIdx.x;
    const int lane = tid & 63;
    const int wid  = tid >> 6;
    const int wr   = wid >> 1;
    const int wc   = wid & 1;
    const int bt   = blockIdx.x >> 6;
    const int jt   = blockIdx.x & 63;
    const int b0   = bt * 64;
    const int j0   = jt * 16;

    f32x4 acc[2][2] = {};

    auto mfma_tile = [&]() {
        #pragma unroll
        for (int ks = 0; ks < 2; ++ks) {
            const int kc = (ks << 2) + (lane >> 4);
            s16x8 a[2], bfr[2];
            #pragma unroll
            for (int m = 0; m < 2; ++m) {
                int row = wr * 32 + m * 16 + (lane & 15);
                a[m] = *(const s16x8*)&At[row * 64 + ((kc ^ (row & 7)) << 3)];
            }
            #pragma unroll
            for (int n = 0; n < 2; ++n) {
                int col = wc * 32 + n * 16 + (lane & 15);
                bfr[n] = *(const s16x8*)&Bt[col * 64 + ((kc ^ (col & 7)) << 3)];
            }
            #pragma unroll
            for (int m = 0; m < 2; ++m)
                #pragma unroll
                for (int n = 0; n < 2; ++n)
                    acc[m][n] = __builtin_amdgcn_mfma_f32_16x16x32_bf16(a[m], bfr[n], acc[m][n], 0, 0, 0);
        }
    };

    for (int kb = 0; kb < Dd; kb += 64) {
        __syncthreads();
        #pragma unroll
        for (int it = 0; it < 4; ++it) {
            int idx = tid + it * 256;
            int row = idx >> 4;
            int k   = (idx & 15) * 4;
            const float4 v = *(const float4*)&x[(size_t)(b0 + row) * (Tlen * Dd) + (size_t)t * Dd + kb + k];
            ushort4 o;
            o.x = f2bf(v.x); o.y = f2bf(v.y); o.z = f2bf(v.z); o.w = f2bf(v.w);
            int dst = row * 64 + (((k >> 3) ^ (row & 7)) << 3) + (k & 7);
            *(ushort4*)&At[dst] = o;
        }
        #pragma unroll
        for (int it = 0; it < 2; ++it) {
            int idx = tid + it * 256;
            int col = idx >> 3;
            int kc  = idx & 7;
            int grow = ((col >> 4) << 10) + j0 + (col & 15);
            uint4 v = *(const uint4*)&Wih[(size_t)grow * Dd + kb + kc * 8];
            *(uint4*)&Bt[col * 64 + ((kc ^ (col & 7)) << 3)] = v;
        }
        __syncthreads();
        mfma_tile();
    }
    for (int kb = 0; kb < Hh; kb += 64) {
        __syncthreads();
        #pragma unroll
        for (int it = 0; it < 2; ++it) {
            int idx = tid + it * 256;
            int row = idx >> 3;
            int kc  = idx & 7;
            uint4 v = *(const uint4*)&h_prev[(size_t)(b0 + row) * Hh + kb + kc * 8];
            *(uint4*)&At[row * 64 + ((kc ^ (row & 7)) << 3)] = v;
        }
        #pragma unroll
        for (int it = 0; it < 2; ++it) {
            int idx = tid + it * 256;
            int col = idx >> 3;
            int kc  = idx & 7;
            int grow = ((col >> 4) << 10) + j0 + (col & 15);
            uint4 v = *(const uint4*)&Whh[(size_t)grow * Hh + kb + kc * 8];
            *(uint4*)&Bt[col * 64 + ((kc ^ (col & 7)) << 3)] = v;
        }
        __syncthreads();
        mfma_tile();
    }

    #pragma unroll
    for (int m = 0; m < 2; ++m)
        #pragma unroll
        for (int n = 0; n < 2; ++n)
            #pragma unroll
            for (int j = 0; j < 4; ++j) {
                int row = wr * 32 + m * 16 + ((lane >> 4) << 2) + j;
                int col = wc * 32 + n * 16 + (lane & 15);
                gates[row * 72 + col] = acc[m][n][j];
            }
    __syncthreads();

    #pragma unroll
    for (int it = 0; it < 4; ++it) {
        int idx = tid + it * 256;
        int row = idx >> 4;
        int cc  = idx & 15;
        int gcol = j0 + cc;
        float gi = gates[row * 72 + cc]      + b_ih[gcol]          + b_hh[gcol];
        float gf = gates[row * 72 + 16 + cc] + b_ih[Hh + gcol]     + b_hh[Hh + gcol];
        float gg = gates[row * 72 + 32 + cc] + b_ih[2 * Hh + gcol] + b_hh[2 * Hh + gcol];
        float go = gates[row * 72 + 48 + cc] + b_ih[3 * Hh + gcol] + b_hh[3 * Hh + gcol];
        float i_ = sigf(gi);
        float f_ = sigf(gf);
        float g_ = tanhfast(gg);
        float o_ = sigf(go);
        size_t cidx = (size_t)(b0 + row) * Hh + gcol;
        float cn = f_ * c[cidx] + i_ * g_;
        c[cidx] = cn;
        float hn = o_ * tanhfast(cn);
        h_next[cidx] = f2bf(hn);
    }
}

// ---------------- FC head ----------------
__global__ void fc_kernel(const ushort* __restrict__ h,
                          const float* __restrict__ Wfc,
                          const float* __restrict__ bfc,
                          float* __restrict__ out) {
    int b = blockIdx.x;
    int w = threadIdx.x >> 6;
    int lane = threadIdx.x & 63;
    float s = 0.f;
    for (int k = lane; k < Hh; k += 64)
        s += bf2f(h[(size_t)b * Hh + k]) * Wfc[w * Hh + k];
    #pragma unroll
    for (int off = 32; off; off >>= 1) s += __shfl_down(s, off);
    if (lane == 0) out[b * NOUT + w] = sigf(s + bfc[w]);
}

// ================= LAUNCH =================

extern "C" void kernel_launch(void* const* d_in, const int* in_sizes, int n_in,
                              void* d_out, int out_size, void* d_ws, size_t ws_size,
                              hipStream_t stream) {
    const float* x    = (const float*)d_in[0];
    const float* W_ih = (const float*)d_in[1];
    const float* W_hh = (const float*)d_in[2];
    const float* b_ih = (const float*)d_in[3];
    const float* b_hh = (const float*)d_in[4];
    const float* W_fc = (const float*)d_in[5];
    const float* b_fc = (const float*)d_in[6];
    float* out = (float*)d_out;
    char* ws = (char*)d_ws;

    // ws layout (fixed part = 14 MB, proven available):
    //   [0, 1 MB)    h ping-pong bf16 [2][256][1024]
    //   [1, 2 MB)    c fp32 [256][1024]
    //   [2, 6 MB)    W_ih bf16 [4096][512]
    //   [6, 14 MB)   W_hh bf16 [4096][1024]
    //   [14 MB, ..)  x bf16: full [256][512][512] (128 MB, T1) or
    //                2 chunk buffers [256][8][512] (4 MB, T2)
    ushort* h_buf  = (ushort*)ws;
    float*  c_ws   = (float*)(ws + (1ull << 20));
    ushort* wih_bf = (ushort*)(ws + (2ull << 20));
    ushort* whh_bf = (ushort*)(ws + (6ull << 20));
    char*   x_ext  = ws + (14ull << 20);

    const size_t FIXED   = 14ull << 20;
    const size_t XFULL   = (size_t)Bsz * Tlen * Dd * 2;        // 128 MB
    const size_t XCHUNK  = (size_t)Bsz * 8 * Dd * 2;           // 2 MB per buffer

    init_kernel<<<256, 256, 0, stream>>>((uint4*)h_buf, (uint4*)c_ws);
    cvt_kernel<<<(G4 * Dd / 4) / 256, 256, 0, stream>>>((const float4*)W_ih, (ushort4*)wih_bf, G4 * Dd / 4);
    cvt_kernel<<<(G4 * Hh / 4) / 256, 256, 0, stream>>>((const float4*)W_hh, (ushort4*)whh_bf, G4 * Hh / 4);

    if (ws_size >= FIXED + XFULL) {
        // T1: convert all of x once; layout [b][t][k] (tstride=512)
        ushort* x_bf = (ushort*)x_ext;
        const int n4 = BT * Dd / 4;
        cvt_kernel<<<n4 / 256, 256, 0, stream>>>((const float4*)x, (ushort4*)x_bf, n4);
        for (int t = 0; t < Tlen; ++t) {
            const ushort* hp = h_buf + (size_t)(t & 1) * Bsz * Hh;
            ushort*       hn = h_buf + (size_t)((t + 1) & 1) * Bsz * Hh;
            lstm_step7<<<512, 256, 0, stream>>>(x_bf, Tlen, t, wih_bf, whh_bf,
                                                hp, hn, c_ws, b_ih, b_hh);
        }
    } else if (ws_size >= FIXED + 2 * XCHUNK) {
        // T2: double-buffered 8-step chunks; layout [b][8][k] (tstride=8)
        ushort* xchunk = (ushort*)x_ext;
        for (int t = 0; t < Tlen; ++t) {
            if ((t & 7) == 0) {
                ushort* dst = xchunk + (size_t)((t >> 3) & 1) * (Bsz * 8 * Dd);
                cvt_xchunk<<<512, 256, 0, stream>>>(x, dst, t);
            }
            const ushort* xb = xchunk + (size_t)((t >> 3) & 1) * (Bsz * 8 * Dd);
            const ushort* hp = h_buf + (size_t)(t & 1) * Bsz * Hh;
            ushort*       hn = h_buf + (size_t)((t + 1) & 1) * Bsz * Hh;
            lstm_step7<<<512, 256, 0, stream>>>(xb, 8, t & 7, wih_bf, whh_bf,
                                                hp, hn, c_ws, b_ih, b_hh);
        }
    } else {
        // T3: proven fallback
        for (int t = 0; t < Tlen; ++t) {
            const ushort* hp = h_buf + (size_t)(t & 1) * Bsz * Hh;
            ushort*       hn = h_buf + (size_t)((t + 1) & 1) * Bsz * Hh;
            lstm_step_fused<<<256, 256, 0, stream>>>(x, wih_bf, whh_bf, b_ih, b_hh, hp, hn, c_ws, t);
        }
    }
    // 512 steps (even) -> final h in buffer 0
    fc_kernel<<<256, 512, 0, stream>>>(h_buf, W_fc, b_fc, out);
}